// Round 1
// baseline (5269.339 us; speedup 1.0000x reference)
//
#include <hip/hip_runtime.h>
#include <cmath>

#define B_   128
#define N_   196
#define ENC_ 2048
#define DEC_ 512
#define ATT_ 512
#define EMB_ 512
#define V_   10000
#define TS_  20   // T-1 decode steps
#define XH_  3072 // EMB + ENC + DEC

__device__ __forceinline__ float sigmoidf_(float x) { return 1.0f / (1.0f + expf(-x)); }

// ---------------------------------------------------------------------------
// mean over N axis of features (B, N, ENC)
__global__ __launch_bounds__(256) void k_mean(const float* __restrict__ f,
                                              float* __restrict__ mean) {
  int b = blockIdx.y;
  int e = blockIdx.x * 256 + threadIdx.x;
  const float* p = f + (size_t)b * N_ * ENC_ + e;
  float s = 0.f;
#pragma unroll 4
  for (int n = 0; n < N_; ++n) s += p[(size_t)n * ENC_];
  mean[b * ENC_ + e] = s * (1.0f / (float)N_);
}

// ---------------------------------------------------------------------------
// C[m, n] = b1[n] (+ b2[n])   -- init for split-K atomic GEMMs
__global__ __launch_bounds__(256) void k_init_bias(float* __restrict__ C, int ldc,
                                                   const float* __restrict__ b1,
                                                   const float* __restrict__ b2, int N) {
  int n = blockIdx.x * 256 + threadIdx.x;
  int m = blockIdx.y;
  if (n < N) C[(size_t)m * ldc + n] = b1[n] + (b2 ? b2[n] : 0.f);
}

// ---------------------------------------------------------------------------
// Generic tiled fp32 GEMM: C(M,N) = A(M,K) @ B(K,N) [+ bias]
// BM=32, BN=64, BK=32; 256 threads; each thread 2x4 outputs.
// gridDim.z > 1 => split-K, atomic accumulate (C must be pre-initialized).
// Requires: M % 32 == 0, (K / gridDim.z) % 32 == 0. N arbitrary.
__global__ __launch_bounds__(256) void k_gemm(
    const float* __restrict__ A, int lda,
    const float* __restrict__ Bm, int ldb,
    const float* __restrict__ bias,
    float* __restrict__ C, int ldc,
    int M, int N, int K, int atomic) {
  __shared__ float Ats[32][33];   // A tile, transposed [k][m], +1 pad
  __shared__ float Bs[32][68];    // B tile [k][n], +4 pad keeps 16B alignment

  const int tid = threadIdx.x;
  const int bm  = blockIdx.y * 32;
  const int bn  = blockIdx.x * 64;
  const int kchunk  = K / gridDim.z;
  const int k_begin = blockIdx.z * kchunk;
  const int k_end   = k_begin + kchunk;

  const int tx = tid & 15;       // output col group
  const int ty = tid >> 4;       // output row group
  const int a_row = tid >> 3;    // 0..31
  const int a_k   = (tid & 7) << 2;
  const int b_k   = tid >> 4;    // 0..15
  const int b_n   = (tid & 15) << 2;
  const bool full_n = (bn + 64 <= N);

  float acc[2][4] = {{0.f, 0.f, 0.f, 0.f}, {0.f, 0.f, 0.f, 0.f}};

  for (int k0 = k_begin; k0 < k_end; k0 += 32) {
    float4 av = *(const float4*)(A + (size_t)(bm + a_row) * lda + (k0 + a_k));
    Ats[a_k + 0][a_row] = av.x;
    Ats[a_k + 1][a_row] = av.y;
    Ats[a_k + 2][a_row] = av.z;
    Ats[a_k + 3][a_row] = av.w;
    if (full_n) {
      *(float4*)&Bs[b_k][b_n]      = *(const float4*)(Bm + (size_t)(k0 + b_k) * ldb + (bn + b_n));
      *(float4*)&Bs[b_k + 16][b_n] = *(const float4*)(Bm + (size_t)(k0 + b_k + 16) * ldb + (bn + b_n));
    } else {
#pragma unroll
      for (int j = 0; j < 4; ++j) {
        int n = bn + b_n + j;
        float v0 = 0.f, v1 = 0.f;
        if (n < N) {
          v0 = Bm[(size_t)(k0 + b_k) * ldb + n];
          v1 = Bm[(size_t)(k0 + b_k + 16) * ldb + n];
        }
        Bs[b_k][b_n + j]      = v0;
        Bs[b_k + 16][b_n + j] = v1;
      }
    }
    __syncthreads();
#pragma unroll
    for (int k = 0; k < 32; ++k) {
      float a0 = Ats[k][ty * 2 + 0];
      float a1 = Ats[k][ty * 2 + 1];
      float b0 = Bs[k][tx * 4 + 0];
      float b1 = Bs[k][tx * 4 + 1];
      float b2 = Bs[k][tx * 4 + 2];
      float b3 = Bs[k][tx * 4 + 3];
      acc[0][0] = fmaf(a0, b0, acc[0][0]);
      acc[0][1] = fmaf(a0, b1, acc[0][1]);
      acc[0][2] = fmaf(a0, b2, acc[0][2]);
      acc[0][3] = fmaf(a0, b3, acc[0][3]);
      acc[1][0] = fmaf(a1, b0, acc[1][0]);
      acc[1][1] = fmaf(a1, b1, acc[1][1]);
      acc[1][2] = fmaf(a1, b2, acc[1][2]);
      acc[1][3] = fmaf(a1, b3, acc[1][3]);
    }
    __syncthreads();
  }

#pragma unroll
  for (int i = 0; i < 2; ++i) {
    int row = bm + ty * 2 + i;
#pragma unroll
    for (int j = 0; j < 4; ++j) {
      int n = bn + tx * 4 + j;
      if (n < N) {
        float* cp = C + (size_t)row * ldc + n;
        if (atomic) atomicAdd(cp, acc[i][j]);
        else        *cp = acc[i][j] + bias[n];
      }
    }
  }
}

// ---------------------------------------------------------------------------
// scores[b,n] = sum_a tanh(u_hs[b,n,a] + w_ah[b,a]) * A_w[a] + A_b
// one wave per (b,n); 4 waves per block
__global__ __launch_bounds__(256) void k_scores(const float* __restrict__ u_hs,
                                                const float* __restrict__ w_ah,
                                                const float* __restrict__ A_w,
                                                const float* __restrict__ A_b,
                                                float* __restrict__ scores) {
  int wave = threadIdx.x >> 6;
  int lane = threadIdx.x & 63;
  int bn = blockIdx.x * 4 + wave;   // 0..25087
  int b  = bn / N_;
  const float* up = u_hs + (size_t)bn * ATT_;
  const float* wp = w_ah + (size_t)b * ATT_;
  float s = 0.f;
#pragma unroll
  for (int j = 0; j < ATT_ / 64; ++j) {
    int a = lane + j * 64;
    s += tanhf(up[a] + wp[a]) * A_w[a];
  }
#pragma unroll
  for (int off = 32; off; off >>= 1) s += __shfl_down(s, off);
  if (lane == 0) scores[bn] = s + A_b[0];
}

// ---------------------------------------------------------------------------
// softmax over n (196) per b; writes alpha directly to output tensor
__global__ __launch_bounds__(256) void k_softmax(const float* __restrict__ scores,
                                                 float* __restrict__ alphas, int t) {
  int b = blockIdx.x;
  int tid = threadIdx.x;
  int w = tid >> 6, lane = tid & 63;
  __shared__ float wm[4], ws[4];
  __shared__ float bmax, bsum;

  float v = (tid < N_) ? scores[b * N_ + tid] : -1e30f;
  float m = v;
#pragma unroll
  for (int off = 32; off; off >>= 1) m = fmaxf(m, __shfl_down(m, off));
  if (lane == 0) wm[w] = m;
  __syncthreads();
  if (tid == 0) bmax = fmaxf(fmaxf(wm[0], wm[1]), fmaxf(wm[2], wm[3]));
  __syncthreads();
  float e = (tid < N_) ? expf(v - bmax) : 0.f;
  float s = e;
#pragma unroll
  for (int off = 32; off; off >>= 1) s += __shfl_down(s, off);
  if (lane == 0) ws[w] = s;
  __syncthreads();
  if (tid == 0) bsum = ws[0] + ws[1] + ws[2] + ws[3];
  __syncthreads();
  if (tid < N_) alphas[((size_t)b * TS_ + t) * N_ + tid] = e / bsum;
}

// ---------------------------------------------------------------------------
// context[b,e] = sum_n alpha[b,n] * features[b,n,e]  -> xh[b, 512+e]
__global__ __launch_bounds__(256) void k_context(const float* __restrict__ features,
                                                 const float* __restrict__ alphas, int t,
                                                 float* __restrict__ xh) {
  int b = blockIdx.y;
  int e = blockIdx.x * 256 + threadIdx.x;
  __shared__ float al[N_];
  if (threadIdx.x < N_) al[threadIdx.x] = alphas[((size_t)b * TS_ + t) * N_ + threadIdx.x];
  __syncthreads();
  const float* fp = features + (size_t)b * N_ * ENC_ + e;
  float s = 0.f;
#pragma unroll 4
  for (int n = 0; n < N_; ++n) s += al[n] * fp[(size_t)n * ENC_];
  xh[(size_t)b * XH_ + EMB_ + e] = s;
}

// ---------------------------------------------------------------------------
// xh[b, 0:512] = emb[captions[b, t]]
__global__ __launch_bounds__(256) void k_embed(const float* __restrict__ emb,
                                               const int* __restrict__ captions, int t,
                                               float* __restrict__ xh) {
  int b = blockIdx.y;
  int k = blockIdx.x * 256 + threadIdx.x;
  int tok = captions[b * 21 + t];
  xh[(size_t)b * XH_ + k] = emb[(size_t)tok * EMB_ + k];
}

// ---------------------------------------------------------------------------
// LSTM cell: consumes gates (B,2048), updates c and writes h into xh[:,2560:]
__global__ __launch_bounds__(256) void k_lstm(const float* __restrict__ gates,
                                              float* __restrict__ c,
                                              float* __restrict__ xh) {
  int b = blockIdx.y;
  int j = blockIdx.x * 256 + threadIdx.x;
  const float* g = gates + (size_t)b * 2048;
  float ig = sigmoidf_(g[j]);
  float fg = sigmoidf_(g[512 + j]);
  float gg = tanhf(g[1024 + j]);
  float og = sigmoidf_(g[1536 + j]);
  float cn = fg * c[b * DEC_ + j] + ig * gg;
  c[b * DEC_ + j] = cn;
  xh[(size_t)b * XH_ + EMB_ + ENC_ + j] = og * tanhf(cn);
}

// ---------------------------------------------------------------------------
extern "C" void kernel_launch(void* const* d_in, const int* in_sizes, int n_in,
                              void* d_out, int out_size, void* d_ws, size_t ws_size,
                              hipStream_t stream) {
  (void)in_sizes; (void)n_in; (void)out_size; (void)ws_size;

  const float* features = (const float*)d_in[0];
  const int*   captions = (const int*)d_in[1];
  const float* emb      = (const float*)d_in[2];
  const float* U_w      = (const float*)d_in[3];
  const float* U_b      = (const float*)d_in[4];
  const float* W_w      = (const float*)d_in[5];
  const float* W_b      = (const float*)d_in[6];
  const float* A_w      = (const float*)d_in[7];
  const float* A_b      = (const float*)d_in[8];
  const float* ih_w     = (const float*)d_in[9];
  const float* ih_b     = (const float*)d_in[10];
  const float* ic_w     = (const float*)d_in[11];
  const float* ic_b     = (const float*)d_in[12];
  const float* Wih      = (const float*)d_in[13];
  const float* Whh      = (const float*)d_in[14];
  const float* bih      = (const float*)d_in[15];
  const float* bhh      = (const float*)d_in[16];
  const float* fcn_w    = (const float*)d_in[17];
  const float* fcn_b    = (const float*)d_in[18];

  float* preds  = (float*)d_out;                              // (B, 20, V)
  float* alphas = (float*)d_out + (size_t)B_ * TS_ * V_;      // (B, 20, N)

  float* ws     = (float*)d_ws;
  float* u_hs   = ws;                                   // B*N*ATT = 12,845,056
  float* mean   = u_hs + (size_t)B_ * N_ * ATT_;        // B*ENC
  float* xh     = mean + (size_t)B_ * ENC_;             // B*3072  [emb|ctx|h]
  float* cbuf   = xh + (size_t)B_ * XH_;                // B*DEC
  float* w_ah   = cbuf + (size_t)B_ * DEC_;             // B*ATT
  float* scores = w_ah + (size_t)B_ * ATT_;             // B*N
  float* gates  = scores + (size_t)B_ * N_;             // B*2048

  // ---- precompute ----
  k_mean<<<dim3(ENC_ / 256, B_), 256, 0, stream>>>(features, mean);
  // h0 -> xh[:, 2560:3072]
  k_gemm<<<dim3(DEC_ / 64, B_ / 32, 1), 256, 0, stream>>>(
      mean, ENC_, ih_w, DEC_, ih_b, xh + EMB_ + ENC_, XH_, B_, DEC_, ENC_, 0);
  // c0
  k_gemm<<<dim3(DEC_ / 64, B_ / 32, 1), 256, 0, stream>>>(
      mean, ENC_, ic_w, DEC_, ic_b, cbuf, DEC_, B_, DEC_, ENC_, 0);
  // u_hs = features @ U_w + U_b   (25088 x 512 x 2048)
  k_gemm<<<dim3(ATT_ / 64, (B_ * N_) / 32, 1), 256, 0, stream>>>(
      features, ENC_, U_w, ATT_, U_b, u_hs, ATT_, B_ * N_, ATT_, ENC_, 0);

  // ---- decode steps ----
  for (int t = 0; t < TS_; ++t) {
    // w_ah = h @ W_w + W_b  (split-K=4, atomic)
    k_init_bias<<<dim3(ATT_ / 256, B_), 256, 0, stream>>>(w_ah, ATT_, W_b, nullptr, ATT_);
    k_gemm<<<dim3(ATT_ / 64, B_ / 32, 4), 256, 0, stream>>>(
        xh + EMB_ + ENC_, XH_, W_w, ATT_, nullptr, w_ah, ATT_, B_, ATT_, DEC_, 1);

    k_scores<<<(B_ * N_) / 4, 256, 0, stream>>>(u_hs, w_ah, A_w, A_b, scores);
    k_softmax<<<B_, 256, 0, stream>>>(scores, alphas, t);
    k_context<<<dim3(ENC_ / 256, B_), 256, 0, stream>>>(features, alphas, t, xh);
    k_embed<<<dim3(EMB_ / 256, B_), 256, 0, stream>>>(emb, captions, t, xh);

    // gates = [emb|ctx] @ Wih + h @ Whh + bih + bhh
    k_init_bias<<<dim3(2048 / 256, B_), 256, 0, stream>>>(gates, 2048, bih, bhh, 2048);
    k_gemm<<<dim3(2048 / 64, B_ / 32, 4), 256, 0, stream>>>(
        xh, XH_, Wih, 2048, nullptr, gates, 2048, B_, 2048, EMB_ + ENC_, 1);
    k_gemm<<<dim3(2048 / 64, B_ / 32, 2), 256, 0, stream>>>(
        xh + EMB_ + ENC_, XH_, Whh, 2048, nullptr, gates, 2048, B_, 2048, DEC_, 1);

    k_lstm<<<dim3(DEC_ / 256, B_), 256, 0, stream>>>(gates, cbuf, xh);

    // preds[:, t, :] = h @ fcn_w + fcn_b
    k_gemm<<<dim3((V_ + 63) / 64, B_ / 32, 1), 256, 0, stream>>>(
        xh + EMB_ + ENC_, XH_, fcn_w, V_, fcn_b, preds + (size_t)t * V_, TS_ * V_,
        B_, V_, DEC_, 0);
  }
}

// Round 2
// 2762.998 us; speedup vs baseline: 1.9071x; 1.9071x over previous
//
#include <hip/hip_runtime.h>
#include <cmath>

#define B_   128
#define N_   196
#define ENC_ 2048
#define DEC_ 512
#define ATT_ 512
#define EMB_ 512
#define V_   10000
#define TS_  20    // T-1 decode steps
#define XH_  3072  // EMB + ENC + DEC   [emb | ctx | h]

typedef unsigned short u16;
typedef short s16x8 __attribute__((ext_vector_type(8)));   // 8 bf16 = 4 VGPRs (MFMA A/B frag)
typedef float f32x4 __attribute__((ext_vector_type(4)));   // MFMA C/D frag
typedef unsigned short u16x4 __attribute__((ext_vector_type(4)));

__device__ __forceinline__ float sigmoidf_(float x) { return 1.0f / (1.0f + expf(-x)); }

__device__ __forceinline__ u16 f2bf(float x) {  // round-to-nearest-even
  union { float f; unsigned u; } v; v.f = x;
  unsigned r = v.u + 0x7fff + ((v.u >> 16) & 1);
  return (u16)(r >> 16);
}
__device__ __forceinline__ float bf2f(u16 h) {
  union { float f; unsigned u; } v; v.u = ((unsigned)h) << 16; return v.f;
}

typedef const __attribute__((address_space(1))) void gas_t;
typedef __attribute__((address_space(3))) void las_t;
__device__ __forceinline__ void gld_lds16(const void* g, void* l) {
  // async global->LDS, 16 B/lane; LDS dest = wave-uniform base + lane*16
  __builtin_amdgcn_global_load_lds((gas_t*)g, (las_t*)l, 16, 0, 0);
}

// ---------------------------------------------------------------------------
// bf16 MFMA GEMM: C(M,N) = A(M,K) @ Bt(N,K)^T [+ bias]
// A row-major bf16 k-contiguous; Bt row-major bf16 k-contiguous (pre-transposed).
// Tile 128x128, BK=32, 256 threads (4 waves, 2x2 wave grid), 16x16x32 MFMA.
// M % 128 == 0 (grid.y = M/128); grid.x covers N (col bound-checked vs Nbound);
// gridDim.z = split-K (atomic=1 path, C pre-initialized with bias).
__global__ __launch_bounds__(256, 2) void k_mfma(
    const u16* __restrict__ A, int lda,
    const u16* __restrict__ Bt, int ldb,
    const float* __restrict__ bias,
    float* __restrict__ C, u16* __restrict__ Cb, int ldc, int Nbound,
    int K, int atomic) {
  __shared__ __align__(16) u16 As[128 * 32];
  __shared__ __align__(16) u16 Bs[128 * 32];

  const int tid = threadIdx.x;
  const int bm = blockIdx.y * 128;
  const int bn = blockIdx.x * 128;
  const int kchunk = K / gridDim.z;
  const int k0 = blockIdx.z * kchunk;
  const int kend = k0 + kchunk;

  // staging: thread -> one 16B chunk; 2 rounds each for A and B (8 KB tiles)
  const int r0 = tid >> 2;          // row 0..63
  const int kb = (tid & 3) * 8;     // k offset 0,8,16,24
  const u16* ga0 = A + (size_t)(bm + r0) * lda + kb;
  const u16* ga1 = A + (size_t)(bm + 64 + r0) * lda + kb;
  const u16* gb0 = Bt + (size_t)(bn + r0) * ldb + kb;
  const u16* gb1 = Bt + (size_t)(bn + 64 + r0) * ldb + kb;
  u16* la0 = As + tid * 8;
  u16* la1 = As + 2048 + tid * 8;
  u16* lb0 = Bs + tid * 8;
  u16* lb1 = Bs + 2048 + tid * 8;

  const int w = tid >> 6;
  const int lane = tid & 63;
  const int wm = (w & 1) * 64;
  const int wn = (w >> 1) * 64;
  const int r16 = lane & 15;
  const int kq = lane >> 4;         // quad 0..3

  f32x4 acc[4][4] = {};

  for (int k = k0; k < kend; k += 32) {
    gld_lds16(ga0 + k, la0);
    gld_lds16(ga1 + k, la1);
    gld_lds16(gb0 + k, lb0);
    gld_lds16(gb1 + k, lb1);
    __syncthreads();   // emits s_waitcnt vmcnt(0) + s_barrier
    s16x8 af[4], bfr[4];
#pragma unroll
    for (int i = 0; i < 4; ++i)
      af[i] = *(const s16x8*)&As[(wm + i * 16 + r16) * 32 + kq * 8];
#pragma unroll
    for (int i = 0; i < 4; ++i)
      bfr[i] = *(const s16x8*)&Bs[(wn + i * 16 + r16) * 32 + kq * 8];
#pragma unroll
    for (int mi = 0; mi < 4; ++mi)
#pragma unroll
      for (int ni = 0; ni < 4; ++ni)
        acc[mi][ni] = __builtin_amdgcn_mfma_f32_16x16x32_bf16(af[mi], bfr[ni], acc[mi][ni], 0, 0, 0);
    __syncthreads();
  }

  // C/D layout: col = lane&15, row = quad*4 + reg  (m89-verified)
#pragma unroll
  for (int ni = 0; ni < 4; ++ni) {
    int col = bn + wn + ni * 16 + r16;
    if (col < Nbound) {
      float bv = bias ? bias[col] : 0.f;
#pragma unroll
      for (int mi = 0; mi < 4; ++mi) {
#pragma unroll
        for (int r = 0; r < 4; ++r) {
          int row = bm + wm + mi * 16 + kq * 4 + r;
          float v = acc[mi][ni][r] + bv;
          if (atomic)      atomicAdd(&C[(size_t)row * ldc + col], v);
          else if (Cb)     Cb[(size_t)row * ldc + col] = f2bf(v);
          else             C[(size_t)row * ldc + col] = v;
        }
      }
    }
  }
}

// ---------------------------------------------------------------------------
// transpose-convert: in fp32 [K][N] (ld=N) -> out bf16 [Nout][ldo], out[n][k]=in[k][n]
// K multiple of 32; rows n in [N, Nout) are zero-filled.
__global__ __launch_bounds__(256) void k_wt(const float* __restrict__ in, int K, int N,
                                            u16* __restrict__ out, int ldo, int Nout) {
  __shared__ float s[32][33];
  int k0 = blockIdx.x * 32, n0 = blockIdx.y * 32;
  int tx = threadIdx.x & 31, ty = threadIdx.x >> 5;  // 32 x 8
#pragma unroll
  for (int i = 0; i < 4; ++i) {
    int k = k0 + ty + i * 8, n = n0 + tx;
    s[ty + i * 8][tx] = (n < N) ? in[(size_t)k * N + n] : 0.f;
  }
  __syncthreads();
#pragma unroll
  for (int i = 0; i < 4; ++i) {
    int n = n0 + ty + i * 8;
    if (n < Nout) out[(size_t)n * ldo + k0 + tx] = f2bf(s[tx][ty + i * 8]);
  }
}

// flat fp32 -> bf16, count multiple of 4 (thread handles 4)
__global__ __launch_bounds__(256) void k_cvt(const float* __restrict__ in,
                                             u16* __restrict__ out) {
  int i = blockIdx.x * 256 + threadIdx.x;
  float4 v = ((const float4*)in)[i];
  u16x4 o; o.x = f2bf(v.x); o.y = f2bf(v.y); o.z = f2bf(v.z); o.w = f2bf(v.w);
  ((u16x4*)out)[i] = o;
}

__global__ __launch_bounds__(256) void k_bias_sum(const float* a, const float* b, float* o) {
  int i = blockIdx.x * 256 + threadIdx.x;
  o[i] = a[i] + b[i];
}

// C[m, :] = b1[:]  (init for split-K atomic GEMM)
__global__ __launch_bounds__(256) void k_init_bias(float* __restrict__ C, int ldc,
                                                   const float* __restrict__ b1) {
  int n = blockIdx.x * 256 + threadIdx.x;
  int m = blockIdx.y;
  C[(size_t)m * ldc + n] = b1[n];
}

// ---------------------------------------------------------------------------
__global__ __launch_bounds__(256) void k_mean(const float* __restrict__ f,
                                              float* __restrict__ mean) {
  int b = blockIdx.y;
  int e = blockIdx.x * 256 + threadIdx.x;
  const float* p = f + (size_t)b * N_ * ENC_ + e;
  float s = 0.f;
#pragma unroll 4
  for (int n = 0; n < N_; ++n) s += p[(size_t)n * ENC_];
  mean[b * ENC_ + e] = s * (1.0f / (float)N_);
}

// scores[b,n] = sum_a tanh(u_hs[b,n,a] + w_ah[b,a]) * A_w[a] + A_b ; 1 wave/(b,n)
__global__ __launch_bounds__(256) void k_scores(const float* __restrict__ u_hs,
                                                const float* __restrict__ w_ah,
                                                const float* __restrict__ A_w,
                                                const float* __restrict__ A_b,
                                                float* __restrict__ scores) {
  int wave = threadIdx.x >> 6;
  int lane = threadIdx.x & 63;
  int bn = blockIdx.x * 4 + wave;
  int b = bn / N_;
  const float* up = u_hs + (size_t)bn * ATT_;
  const float* wp = w_ah + (size_t)b * ATT_;
  float s = 0.f;
#pragma unroll
  for (int j = 0; j < ATT_ / 64; ++j) {
    int a = lane + j * 64;
    s += tanhf(up[a] + wp[a]) * A_w[a];
  }
#pragma unroll
  for (int off = 32; off; off >>= 1) s += __shfl_down(s, off);
  if (lane == 0) scores[bn] = s + A_b[0];
}

__global__ __launch_bounds__(256) void k_softmax(const float* __restrict__ scores,
                                                 float* __restrict__ alphas, int t) {
  int b = blockIdx.x, tid = threadIdx.x;
  int w = tid >> 6, lane = tid & 63;
  __shared__ float wm[4], ws[4];
  __shared__ float bmax, bsum;
  float v = (tid < N_) ? scores[b * N_ + tid] : -1e30f;
  float m = v;
#pragma unroll
  for (int off = 32; off; off >>= 1) m = fmaxf(m, __shfl_down(m, off));
  if (lane == 0) wm[w] = m;
  __syncthreads();
  if (tid == 0) bmax = fmaxf(fmaxf(wm[0], wm[1]), fmaxf(wm[2], wm[3]));
  __syncthreads();
  float e = (tid < N_) ? expf(v - bmax) : 0.f;
  float s = e;
#pragma unroll
  for (int off = 32; off; off >>= 1) s += __shfl_down(s, off);
  if (lane == 0) ws[w] = s;
  __syncthreads();
  if (tid == 0) bsum = ws[0] + ws[1] + ws[2] + ws[3];
  __syncthreads();
  if (tid < N_) alphas[((size_t)b * TS_ + t) * N_ + tid] = e / bsum;
}

// context[b,e] = sum_n alpha[b,n] * feat_bf[b,n,e]  -> xh_bf[b, 512+e] (bf16)
__global__ __launch_bounds__(256) void k_context(const u16* __restrict__ feat_bf,
                                                 const float* __restrict__ alphas, int t,
                                                 u16* __restrict__ xh_bf) {
  int b = blockIdx.y;
  int e = blockIdx.x * 1024 + threadIdx.x * 4;
  __shared__ float al[N_];
  if (threadIdx.x < N_) al[threadIdx.x] = alphas[((size_t)b * TS_ + t) * N_ + threadIdx.x];
  __syncthreads();
  const u16* fp = feat_bf + (size_t)b * N_ * ENC_ + e;
  float s0 = 0, s1 = 0, s2 = 0, s3 = 0;
#pragma unroll 2
  for (int n = 0; n < N_; ++n) {
    u16x4 v = *(const u16x4*)(fp + (size_t)n * ENC_);
    float a = al[n];
    s0 += a * bf2f(v.x); s1 += a * bf2f(v.y);
    s2 += a * bf2f(v.z); s3 += a * bf2f(v.w);
  }
  u16x4 o; o.x = f2bf(s0); o.y = f2bf(s1); o.z = f2bf(s2); o.w = f2bf(s3);
  *(u16x4*)(xh_bf + (size_t)b * XH_ + EMB_ + e) = o;
}

// xh_bf[b, 0:512] = bf16(emb[captions[b, t]])
__global__ __launch_bounds__(256) void k_embed(const float* __restrict__ emb,
                                               const int* __restrict__ captions, int t,
                                               u16* __restrict__ xh_bf) {
  int b = blockIdx.y;
  int k = blockIdx.x * 256 + threadIdx.x;
  int tok = captions[b * 21 + t];
  xh_bf[(size_t)b * XH_ + k] = f2bf(emb[(size_t)tok * EMB_ + k]);
}

// LSTM cell: gates fp32 (B,2048) -> update c (fp32), h -> xh_bf[:, 2560:3072]
__global__ __launch_bounds__(256) void k_lstm(const float* __restrict__ gates,
                                              float* __restrict__ c,
                                              u16* __restrict__ xh_bf) {
  int b = blockIdx.y;
  int j = blockIdx.x * 256 + threadIdx.x;
  const float* g = gates + (size_t)b * 2048;
  float ig = sigmoidf_(g[j]);
  float fg = sigmoidf_(g[512 + j]);
  float gg = tanhf(g[1024 + j]);
  float og = sigmoidf_(g[1536 + j]);
  float cn = fg * c[b * DEC_ + j] + ig * gg;
  c[b * DEC_ + j] = cn;
  xh_bf[(size_t)b * XH_ + EMB_ + ENC_ + j] = f2bf(og * tanhf(cn));
}

// ---------------------------------------------------------------------------
extern "C" void kernel_launch(void* const* d_in, const int* in_sizes, int n_in,
                              void* d_out, int out_size, void* d_ws, size_t ws_size,
                              hipStream_t stream) {
  (void)in_sizes; (void)n_in; (void)out_size; (void)ws_size;

  const float* features = (const float*)d_in[0];
  const int*   captions = (const int*)d_in[1];
  const float* emb      = (const float*)d_in[2];
  const float* U_w      = (const float*)d_in[3];
  const float* U_b      = (const float*)d_in[4];
  const float* W_w      = (const float*)d_in[5];
  const float* W_b      = (const float*)d_in[6];
  const float* A_w      = (const float*)d_in[7];
  const float* A_b      = (const float*)d_in[8];
  const float* ih_w     = (const float*)d_in[9];
  const float* ih_b     = (const float*)d_in[10];
  const float* ic_w     = (const float*)d_in[11];
  const float* ic_b     = (const float*)d_in[12];
  const float* Wih      = (const float*)d_in[13];
  const float* Whh      = (const float*)d_in[14];
  const float* bih      = (const float*)d_in[15];
  const float* bhh      = (const float*)d_in[16];
  const float* fcn_w    = (const float*)d_in[17];
  const float* fcn_b    = (const float*)d_in[18];

  float* preds  = (float*)d_out;                          // (B, 20, V)
  float* alphas = (float*)d_out + (size_t)B_ * TS_ * V_;  // (B, 20, N)

  // workspace layout (float units)
  float* p = (float*)d_ws;
  float* u_hs   = p;            p += (size_t)B_ * N_ * ATT_;       // 12,845,056 f
  u16*   feat_bf = (u16*)p;     p += (size_t)B_ * N_ * ENC_ / 2;   // bf16 (B*N, ENC)
  u16*   WcatT  = (u16*)p;      p += (size_t)2048 * XH_ / 2;       // [2048][3072]
  u16*   fcn_wT = (u16*)p;      p += (size_t)10112 * DEC_ / 2;     // [10112][512], padded
  u16*   U_wT   = (u16*)p;      p += (size_t)ATT_ * ENC_ / 2;      // [512][2048]
  u16*   W_wT   = (u16*)p;      p += (size_t)ATT_ * DEC_ / 2;      // [512][512]
  u16*   ih_wT  = (u16*)p;      p += (size_t)DEC_ * ENC_ / 2;      // [512][2048]
  u16*   ic_wT  = (u16*)p;      p += (size_t)DEC_ * ENC_ / 2;      // [512][2048]
  u16*   mean_bf = (u16*)p;     p += (size_t)B_ * ENC_ / 2;
  u16*   xh_bf  = (u16*)p;      p += (size_t)B_ * XH_ / 2;         // [emb|ctx|h] bf16
  float* mean   = p;            p += (size_t)B_ * ENC_;
  float* cbuf   = p;            p += (size_t)B_ * DEC_;
  float* w_ah   = p;            p += (size_t)B_ * ATT_;
  float* scores = p;            p += (size_t)B_ * N_;
  float* gates  = p;            p += (size_t)B_ * 2048;
  float* bg     = p;            p += 2048;

  // ---- one-time conversions ----
  k_cvt<<<(B_ * N_ * ENC_) / 1024, 256, 0, stream>>>(features, feat_bf);
  k_mean<<<dim3(ENC_ / 256, B_), 256, 0, stream>>>(features, mean);
  k_cvt<<<(B_ * ENC_) / 1024, 256, 0, stream>>>(mean, mean_bf);
  k_wt<<<dim3(ENC_ / 32, ATT_ / 32), 256, 0, stream>>>(U_w, ENC_, ATT_, U_wT, ENC_, ATT_);
  k_wt<<<dim3(DEC_ / 32, ATT_ / 32), 256, 0, stream>>>(W_w, DEC_, ATT_, W_wT, DEC_, ATT_);
  k_wt<<<dim3(ENC_ / 32, DEC_ / 32), 256, 0, stream>>>(ih_w, ENC_, DEC_, ih_wT, ENC_, DEC_);
  k_wt<<<dim3(ENC_ / 32, DEC_ / 32), 256, 0, stream>>>(ic_w, ENC_, DEC_, ic_wT, ENC_, DEC_);
  k_wt<<<dim3(2560 / 32, 2048 / 32), 256, 0, stream>>>(Wih, 2560, 2048, WcatT, XH_, 2048);
  k_wt<<<dim3(DEC_ / 32, 2048 / 32), 256, 0, stream>>>(Whh, DEC_, 2048, WcatT + 2560, XH_, 2048);
  k_wt<<<dim3(DEC_ / 32, 10112 / 32), 256, 0, stream>>>(fcn_w, DEC_, V_, fcn_wT, DEC_, 10112);
  k_bias_sum<<<2048 / 256, 256, 0, stream>>>(bih, bhh, bg);

  // h0 -> xh_bf[:, 2560:] (bf16 out);  c0 -> cbuf (fp32)
  k_mfma<<<dim3(4, 1, 1), 256, 0, stream>>>(mean_bf, ENC_, ih_wT, ENC_, ih_b,
                                            nullptr, xh_bf + EMB_ + ENC_, XH_, DEC_, ENC_, 0);
  k_mfma<<<dim3(4, 1, 1), 256, 0, stream>>>(mean_bf, ENC_, ic_wT, ENC_, ic_b,
                                            cbuf, nullptr, DEC_, DEC_, ENC_, 0);
  // u_hs = features @ U_w + U_b   (25088 x 512 x 2048)
  k_mfma<<<dim3(ATT_ / 128, (B_ * N_) / 128, 1), 256, 0, stream>>>(
      feat_bf, ENC_, U_wT, ENC_, U_b, u_hs, nullptr, ATT_, ATT_, ENC_, 0);

  // ---- decode steps ----
  for (int t = 0; t < TS_; ++t) {
    // w_ah = h @ W_w + W_b
    k_mfma<<<dim3(ATT_ / 128, 1, 1), 256, 0, stream>>>(
        xh_bf + EMB_ + ENC_, XH_, W_wT, DEC_, W_b, w_ah, nullptr, ATT_, ATT_, DEC_, 0);

    k_scores<<<(B_ * N_) / 4, 256, 0, stream>>>(u_hs, w_ah, A_w, A_b, scores);
    k_softmax<<<B_, 256, 0, stream>>>(scores, alphas, t);
    k_context<<<dim3(2, B_), 256, 0, stream>>>(feat_bf, alphas, t, xh_bf);
    k_embed<<<dim3(EMB_ / 256, B_), 256, 0, stream>>>(emb, captions, t, xh_bf);

    // gates = xh @ Wcat + (bih + bhh)   split-K=4, atomic
    k_init_bias<<<dim3(2048 / 256, B_), 256, 0, stream>>>(gates, 2048, bg);
    k_mfma<<<dim3(2048 / 128, 1, 4), 256, 0, stream>>>(
        xh_bf, XH_, WcatT, XH_, nullptr, gates, nullptr, 2048, 2048, XH_, 1);

    k_lstm<<<dim3(DEC_ / 256, B_), 256, 0, stream>>>(gates, cbuf, xh_bf);

    // preds[:, t, :] = h @ fcn_w + fcn_b   (N=10000, padded Bt to 10112)
    k_mfma<<<dim3(10112 / 128, 1, 1), 256, 0, stream>>>(
        xh_bf + EMB_ + ENC_, XH_, fcn_wT, DEC_, fcn_b,
        preds + (size_t)t * V_, nullptr, TS_ * V_, V_, DEC_, 0);
  }
}